// Round 2
// baseline (664.292 us; speedup 1.0000x reference)
//
#include <hip/hip_runtime.h>

#define Bn  4
#define Hn  256
#define Wn  256
#define Cn  16
#define NTn 9
#define HWn (Hn*Wn)
#define KF  129      // W/2 + 1
#define CCn 2        // channel chunk for Y intermediate
#define PI_F 3.14159265358979323846f

// ---------------------------------------------------------------------------
// In-LDS radix-2 DIT FFT of length 256, executed by a 64-lane group.
// Data must be loaded bit-reversed. sign = -1 forward, +1 inverse (unscaled).
// ---------------------------------------------------------------------------
__device__ __forceinline__ void fft256_lds(float2* s, int lane, float sign) {
#pragma unroll
  for (int st = 0; st < 8; ++st) {
    __syncthreads();
    const int half = 1 << st;
    const float f = sign * PI_F / (float)half;
#pragma unroll
    for (int r = 0; r < 2; ++r) {
      int bf  = lane + (r << 6);           // butterfly id 0..127
      int pos = bf & (half - 1);
      int i0  = ((bf >> st) << (st + 1)) + pos;
      int i1  = i0 + half;
      float th = f * (float)pos;
      float sw, cw;
      __sincosf(th, &sw, &cw);
      float2 u = s[i0], v = s[i1];
      float vr = v.x * cw - v.y * sw;
      float vi = v.x * sw + v.y * cw;
      s[i0] = make_float2(u.x + vr, u.y + vi);
      s[i1] = make_float2(u.x - vr, u.y - vi);
    }
  }
  __syncthreads();
}

// ---------------------------------------------------------------------------
// Transpose (B,H,W,C) -> planar (B*C, H*W) for coalesced plane access.
// ---------------------------------------------------------------------------
__global__ void k_transpose(const float* __restrict__ inp, float* __restrict__ P) {
  __shared__ float tile[16][17];
  int g  = blockIdx.x * 16;                 // base pixel in flat b*HW space
  int px = threadIdx.x & 15, py = threadIdx.x >> 4;
  tile[py][px] = inp[(size_t)(g + py) * Cn + px];
  __syncthreads();
  int b = g / HWn, p0 = g - b * HWn;
  int c2 = threadIdx.x >> 4, p2 = threadIdx.x & 15;
  P[(size_t)(b * Cn + c2) * HWn + p0 + p2] = tile[p2][c2];
}

// ---------------------------------------------------------------------------
// Warp index map: idx[t, i*W+j] = yi*W+xi or -1 if out of bounds.
// ---------------------------------------------------------------------------
__global__ void k_idx(const float* __restrict__ T, int* __restrict__ idx) {
#pragma clang fp contract(off)
  int g = blockIdx.x * blockDim.x + threadIdx.x;
  if (g >= NTn * HWn) return;
  int t = g / HWn, pix = g - t * HWn;
  int i = pix >> 8, j = pix & 255;
  const float* a = T + t * 8;
  float x = (float)j, y = (float)i;
  float kk = a[6] * x + a[7] * y + 1.0f;
  float xf = (a[0] * x + a[1] * y + a[2]) / kk;
  float yf = (a[3] * x + a[4] * y + a[5]) / kk;
  float xr = rintf(xf), yr = rintf(yf);       // round-half-even, matches jnp.round
  bool valid = (xr >= 0.f) && (xr < (float)Wn) && (yr >= 0.f) && (yr < (float)Hn);
  idx[g] = valid ? ((int)yr * Wn + (int)xr) : -1;
}

// ---------------------------------------------------------------------------
// Norms
// ---------------------------------------------------------------------------
__global__ void k_norm_x(const float* __restrict__ P, float* __restrict__ nx) {
  int plane = blockIdx.x;                     // b*C + c
  const float* p = P + (size_t)plane * HWn;
  float s = 0.f;
  for (int i = threadIdx.x; i < HWn; i += 256) { float v = p[i]; s += v * v; }
  __shared__ float red[256];
  red[threadIdx.x] = s; __syncthreads();
  for (int o = 128; o > 0; o >>= 1) {
    if (threadIdx.x < o) red[threadIdx.x] += red[threadIdx.x + o];
    __syncthreads();
  }
  if (!threadIdx.x) nx[plane] = sqrtf(red[0]);
}

__global__ void k_norm_y(const float* __restrict__ P, const int* __restrict__ idx,
                         float* __restrict__ ny) {
  int blk = blockIdx.x;                       // (t*B + b)*C + c
  int c = blk % Cn, tb = blk / Cn;
  int b = tb % Bn, t = tb / Bn;
  const float* pl = P + (size_t)(b * Cn + c) * HWn;
  const int* ix = idx + (size_t)t * HWn;
  float s = 0.f;
  for (int p = threadIdx.x; p < HWn; p += 256) {
    int id = ix[p];
    if (id >= 0) { float v = pl[id]; s += v * v; }
  }
  __shared__ float red[256];
  red[threadIdx.x] = s; __syncthreads();
  for (int o = 128; o > 0; o >>= 1) {
    if (threadIdx.x < o) red[threadIdx.x] += red[threadIdx.x + o];
    __syncthreads();
  }
  if (!threadIdx.x) ny[blk] = sqrtf(red[0]);
}

// ---------------------------------------------------------------------------
// Row FFT of x: per (b,c,row i) real FFT-256, keep k=0..128.
// Store transposed: Fx[(b*C+c)][k][i]  (so column pass reads contiguously).
// ---------------------------------------------------------------------------
__global__ void k_xrow(const float* __restrict__ P, float2* __restrict__ Fx) {
  __shared__ float2 sb[4][256];
  int grp = threadIdx.x >> 6, lane = threadIdx.x & 63;
  int item = blockIdx.x * 4 + grp;            // (b*C+c)*H + i
  bool act = item < Bn * Cn * Hn;
  float2* s = sb[grp];
  int plane = item >> 8, i = item & 255;
  if (act) {
    const float* row = P + (size_t)plane * HWn + (size_t)i * Wn;
#pragma unroll
    for (int q = 0; q < 4; ++q) {
      int j = lane + (q << 6);
      int rv = __brev((unsigned)j) >> 24;
      s[rv] = make_float2(row[j], 0.f);
    }
  }
  fft256_lds(s, lane, -1.f);
  if (act) {
    for (int k = lane; k < KF; k += 64)
      Fx[((size_t)plane * KF + k) * Hn + i] = s[k];
  }
}

// ---------------------------------------------------------------------------
// Generic in-place FFT along the contiguous (last, length-256) axis.
// Used for: forward column FFT of Fx (sign=-1), inverse column FFT of G (+1).
// ---------------------------------------------------------------------------
__global__ void k_colfft(float2* __restrict__ D, int nItems, float sign) {
  __shared__ float2 sb[4][256];
  int grp = threadIdx.x >> 6, lane = threadIdx.x & 63;
  int item = blockIdx.x * 4 + grp;
  bool act = item < nItems;
  float2* s = sb[grp];
  float2* Dp = D + (size_t)item * Hn;
  if (act) {
#pragma unroll
    for (int q = 0; q < 4; ++q) {
      int i = lane + (q << 6);
      int rv = __brev((unsigned)i) >> 24;
      s[rv] = Dp[i];
    }
  }
  fft256_lds(s, lane, sign);
  if (act) {
#pragma unroll
    for (int q = 0; q < 4; ++q) {
      int i = lane + (q << 6);
      Dp[i] = s[i];
    }
  }
}

// ---------------------------------------------------------------------------
// Row FFT of warped y for a channel chunk [c0, c0+CCn).
// Y layout: [(t*B+b)*CC + cc][k][i]
// ---------------------------------------------------------------------------
__global__ void k_yrow(const float* __restrict__ P, const int* __restrict__ idx,
                       float2* __restrict__ Y, int c0) {
  __shared__ float2 sb[4][256];
  int grp = threadIdx.x >> 6, lane = threadIdx.x & 63;
  int item = blockIdx.x * 4 + grp;            // ((t*B+b)*CC+cc)*H + i
  bool act = item < NTn * Bn * CCn * Hn;
  float2* s = sb[grp];
  int i = item & 255;
  int rem = item >> 8;                        // (t*B+b)*CC + cc
  int cc = rem % CCn, tb = rem / CCn;
  int b = tb % Bn, t = tb / Bn;
  if (act) {
    const float* pl = P + (size_t)(b * Cn + c0 + cc) * HWn;
    const int* ix = idx + (size_t)t * HWn + (size_t)i * Wn;
#pragma unroll
    for (int q = 0; q < 4; ++q) {
      int j = lane + (q << 6);
      int id = ix[j];
      float v = (id >= 0) ? pl[id] : 0.f;
      int rv = __brev((unsigned)j) >> 24;
      s[rv] = make_float2(v, 0.f);
    }
  }
  fft256_lds(s, lane, -1.f);
  if (act) {
    for (int k = lane; k < KF; k += 64)
      Y[((size_t)rem * KF + k) * Hn + i] = s[k];
  }
}

// ---------------------------------------------------------------------------
// Column FFT of y + fused Fx*conj(Fy)*scale accumulation over channel chunk.
// One 64-thread block per (t,b,k). G layout: [t*B+b][k][r], r = row frequency.
// ---------------------------------------------------------------------------
__global__ void k_ycol(const float2* __restrict__ Y, const float2* __restrict__ Fx,
                       const float* __restrict__ nx, const float* __restrict__ ny,
                       float2* __restrict__ G, int c0) {
  __shared__ float2 sb[256];
  int lane = threadIdx.x;                     // block = 64
  int item = blockIdx.x;                      // (t*B+b)*KF + k
  int k = item % KF, tb = item / KF;
  int b = tb % Bn, t = tb / Bn;
  float2 acc[4];
  float2* Gp = G + ((size_t)tb * KF + k) * Hn;
  if (c0 == 0) {
#pragma unroll
    for (int q = 0; q < 4; ++q) acc[q] = make_float2(0.f, 0.f);
  } else {
#pragma unroll
    for (int q = 0; q < 4; ++q) acc[q] = Gp[lane + (q << 6)];
  }
  for (int cc = 0; cc < CCn; ++cc) {
    int c = c0 + cc;
    const float2* Yp = Y + ((size_t)(tb * CCn + cc) * KF + k) * Hn;
    __syncthreads();
#pragma unroll
    for (int q = 0; q < 4; ++q) {
      int i = lane + (q << 6);
      int rv = __brev((unsigned)i) >> 24;
      sb[rv] = Yp[i];
    }
    fft256_lds(sb, lane, -1.f);
    float sc = 1.0f / ((float)Cn * (nx[b * Cn + c] * ny[(t * Bn + b) * Cn + c] + 1e-12f));
    const float2* Fxp = Fx + ((size_t)(b * Cn + c) * KF + k) * Hn;
#pragma unroll
    for (int q = 0; q < 4; ++q) {
      int r = lane + (q << 6);
      float2 fy = sb[r];
      float2 fx = Fxp[r];
      acc[q].x += sc * (fx.x * fy.x + fx.y * fy.y);   // fx * conj(fy)
      acc[q].y += sc * (fx.y * fy.x - fx.x * fy.y);
    }
  }
#pragma unroll
  for (int q = 0; q < 4; ++q) Gp[lane + (q << 6)] = acc[q];
}

// ---------------------------------------------------------------------------
// Hermitian-extend over k, inverse FFT along width, scale, write out[b,i,j,t].
// ---------------------------------------------------------------------------
__global__ void k_irow(const float2* __restrict__ G, float* __restrict__ out) {
  __shared__ float2 sb[4][256];
  int grp = threadIdx.x >> 6, lane = threadIdx.x & 63;
  int item = blockIdx.x * 4 + grp;            // tb*H + i (i = spatial row)
  bool act = item < NTn * Bn * Hn;
  float2* s = sb[grp];
  int i = item & 255, tb = item >> 8;
  const float2* Gp = G + (size_t)tb * KF * Hn + i;
  if (act) {
#pragma unroll
    for (int q = 0; q < 4; ++q) {
      int k = lane + (q << 6);
      float2 z;
      if (k <= 128) {
        z = Gp[(size_t)k * Hn];
      } else {
        float2 w = Gp[(size_t)(256 - k) * Hn];
        z = make_float2(w.x, -w.y);
      }
      int rv = __brev((unsigned)k) >> 24;
      s[rv] = z;
    }
  }
  fft256_lds(s, lane, 1.f);
  if (act) {
    int b = tb % Bn, t = tb / Bn;
    float* op = out + ((size_t)(b * Hn + i) * Wn) * NTn + t;
    const float scale = 1.0f / ((float)Hn * (float)Wn);
#pragma unroll
    for (int q = 0; q < 4; ++q) {
      int j = lane + (q << 6);
      op[(size_t)j * NTn] = s[j].x * scale;
    }
  }
}

// ---------------------------------------------------------------------------
extern "C" void kernel_launch(void* const* d_in, const int* in_sizes, int n_in,
                              void* d_out, int out_size, void* d_ws, size_t ws_size,
                              hipStream_t stream) {
  const float* inp = (const float*)d_in[0];   // (B,H,W,C) f32
  const float* T   = (const float*)d_in[1];   // (NT,8) f32
  float* out = (float*)d_out;                 // (B,H,W,NT) f32
  char* ws = (char*)d_ws;

  size_t off = 0;
  float* P   = (float*)(ws + off); off += (size_t)Bn * Cn * HWn * sizeof(float);        // 16.8 MB
  int*   idx = (int*)  (ws + off); off += (size_t)NTn * HWn * sizeof(int);              // 2.4 MB
  float* nx  = (float*)(ws + off); off += 64 * sizeof(float);
  float* ny  = (float*)(ws + off); off += 576 * sizeof(float);
  float2* Fx = (float2*)(ws + off); off += (size_t)Bn * Cn * KF * Hn * sizeof(float2);  // 16.9 MB
  float2* G  = (float2*)(ws + off); off += (size_t)NTn * Bn * KF * Hn * sizeof(float2); // 9.5 MB
  float2* Y  = (float2*)(ws + off); off += (size_t)NTn * Bn * CCn * KF * Hn * sizeof(float2); // 19 MB
  (void)off; (void)ws_size; (void)in_sizes; (void)n_in; (void)out_size;

  k_transpose<<<Bn * HWn / 16, 256, 0, stream>>>(inp, P);
  k_idx<<<(NTn * HWn + 255) / 256, 256, 0, stream>>>(T, idx);
  k_norm_x<<<Bn * Cn, 256, 0, stream>>>(P, nx);
  k_norm_y<<<NTn * Bn * Cn, 256, 0, stream>>>(P, idx, ny);
  k_xrow<<<Bn * Cn * Hn / 4, 256, 0, stream>>>(P, Fx);
  // Forward column FFT of Fx (the stage that was missing): Fx[plane][k][i] -> [plane][k][r]
  k_colfft<<<(Bn * Cn * KF + 3) / 4, 256, 0, stream>>>(Fx, Bn * Cn * KF, -1.f);

  for (int c0 = 0; c0 < Cn; c0 += CCn) {
    k_yrow<<<NTn * Bn * CCn * Hn / 4, 256, 0, stream>>>(P, idx, Y, c0);
    k_ycol<<<NTn * Bn * KF, 64, 0, stream>>>(Y, Fx, nx, ny, G, c0);
  }

  // Inverse column FFT of G (row-frequency -> spatial row), in place.
  k_colfft<<<(NTn * Bn * KF + 3) / 4, 256, 0, stream>>>(G, NTn * Bn * KF, 1.f);
  k_irow<<<NTn * Bn * Hn / 4, 256, 0, stream>>>(G, out);
}